// Round 1
// baseline (1548.784 us; speedup 1.0000x reference)
//
#include <hip/hip_runtime.h>
#include <math.h>

#define D 64
#define K 4096
#define N 65536

// ---------------- ws layout (in floats) ----------------
// [counts K][sums K*D][scalars 8][e2 K][e_t K*D][enc N (int)]
#define WS_COUNTS 0
#define WS_SUMS   (WS_COUNTS + K)
#define WS_SCAL   (WS_SUMS + K * D)          // 0=loss_acc, 1=h_acc, 2=n_acc
#define WS_E2     (WS_SCAL + 8)
#define WS_ET     (WS_E2 + K)
#define WS_ENC    (WS_ET + K * D)
#define WS_ZERO_FLOATS (WS_SCAL + 8)         // zero counts+sums+scalars

// ---------------- prep: transpose e [D,K] -> e_t [K,D] ----------------
__global__ __launch_bounds__(256) void k_transpose(const float* __restrict__ e,
                                                   float* __restrict__ et) {
    int i = blockIdx.x * 256 + threadIdx.x;   // i = d*K + k (k fastest)
    int d = i >> 12;
    int k = i & (K - 1);
    et[k * D + d] = e[i];
}

// ---------------- prep: e2[k] = sum_d e[d][k]^2 ----------------
__global__ __launch_bounds__(256) void k_e2(const float* __restrict__ e,
                                            float* __restrict__ e2) {
    int k = blockIdx.x * 256 + threadIdx.x;
    float a = 0.0f;
    for (int d = 0; d < D; ++d) {
        float v = e[d * K + k];
        a = fmaf(v, v, a);
    }
    e2[k] = a;
}

// ---------------- main: per-token argmin over K codes ----------------
// lane = token (64 tokens/block), each wave covers a K-quarter.
__global__ __launch_bounds__(256) void k_argmin(const float* __restrict__ x,
                                                const float* __restrict__ et,
                                                const float* __restrict__ e2,
                                                int* __restrict__ enc) {
    const int lane = threadIdx.x & 63;
    const int wave = __builtin_amdgcn_readfirstlane(threadIdx.x >> 6);
    const int tokBase = blockIdx.x * 64;
    const int tok = tokBase + lane;

    // x row resident in 64 VGPRs
    float4 xr[16];
    const float4* xp = (const float4*)(x + (size_t)tok * D);
#pragma unroll
    for (int j = 0; j < 16; ++j) xr[j] = xp[j];

    float best = 3.4e38f;
    int bidx = 0;
    const int k0 = wave * (K / 4);
    for (int k = k0; k < k0 + K / 4; ++k) {
        const float* p = et + (size_t)k * D;   // wave-uniform -> s_load
        float s0 = 0.f, s1 = 0.f, s2 = 0.f, s3 = 0.f;
#pragma unroll
        for (int j = 0; j < 4; ++j) {
            const float4 a0 = xr[4 * j + 0];
            const float4 a1 = xr[4 * j + 1];
            const float4 a2 = xr[4 * j + 2];
            const float4 a3 = xr[4 * j + 3];
            const float* q = p + 16 * j;
            s0 = fmaf(a0.x, q[0],  s0); s0 = fmaf(a0.y, q[1],  s0);
            s0 = fmaf(a0.z, q[2],  s0); s0 = fmaf(a0.w, q[3],  s0);
            s1 = fmaf(a1.x, q[4],  s1); s1 = fmaf(a1.y, q[5],  s1);
            s1 = fmaf(a1.z, q[6],  s1); s1 = fmaf(a1.w, q[7],  s1);
            s2 = fmaf(a2.x, q[8],  s2); s2 = fmaf(a2.y, q[9],  s2);
            s2 = fmaf(a2.z, q[10], s2); s2 = fmaf(a2.w, q[11], s2);
            s3 = fmaf(a3.x, q[12], s3); s3 = fmaf(a3.y, q[13], s3);
            s3 = fmaf(a3.z, q[14], s3); s3 = fmaf(a3.w, q[15], s3);
        }
        float dot = (s0 + s1) + (s2 + s3);
        float dist = fmaf(-2.0f, dot, e2[k]);  // x^2 omitted: constant per row
        if (dist < best) { best = dist; bidx = k; }   // strict < -> first index
    }

    // combine the 4 K-quarters (ascending wave = ascending k: ties keep first)
    __shared__ float sval[4][64];
    __shared__ int   sidx[4][64];
    sval[wave][lane] = best;
    sidx[wave][lane] = bidx;
    __syncthreads();
    if (threadIdx.x < 64) {
        float bv = sval[0][lane];
        int   bi = sidx[0][lane];
#pragma unroll
        for (int w = 1; w < 4; ++w) {
            float v = sval[w][lane];
            int   i2 = sidx[w][lane];
            if (v < bv) { bv = v; bi = i2; }
        }
        enc[tokBase + lane] = bi;
    }
}

// ---------------- gather/scatter: quantized_st, loss, counts, sums ----------------
// one wave per token, lane = d
__global__ __launch_bounds__(256) void k_scatter(const float* __restrict__ x,
                                                 const float* __restrict__ et,
                                                 const int* __restrict__ enc,
                                                 float* __restrict__ out_q,
                                                 float* __restrict__ counts,
                                                 float* __restrict__ sums,
                                                 float* __restrict__ scal) {
    const int lane = threadIdx.x & 63;
    const int wave = __builtin_amdgcn_readfirstlane(threadIdx.x >> 6);
    const int tok = blockIdx.x * 4 + wave;
    const int idx = enc[tok];

    const float xv = x[(size_t)tok * D + lane];
    const float qv = et[(size_t)idx * D + lane];
    float t = qv - xv;                       // quantized - x
    out_q[(size_t)tok * D + lane] = xv + t;  // straight-through = x + (q - x)
    float sq = t * t;
#pragma unroll
    for (int off = 32; off > 0; off >>= 1) sq += __shfl_xor(sq, off, 64);

    atomicAdd(&sums[(size_t)idx * D + lane], xv);
    if (lane == 0) {
        atomicAdd(&scal[0], sq);
        atomicAdd(&counts[idx], 1.0f);
    }
}

// ---------------- per-k stats: new_cs, partial n, partial entropy ----------------
__global__ __launch_bounds__(256) void k_stats(const float* __restrict__ counts,
                                               const float* __restrict__ cs,
                                               float* __restrict__ out_ncs,
                                               float* __restrict__ scal) {
    const int k = blockIdx.x * 256 + threadIdx.x;
    const int lane = threadIdx.x & 63;
    const int wave = threadIdx.x >> 6;
    float c = counts[k];
    float ncs = 0.1f * c + 0.9f * cs[k];
    out_ncs[k] = ncs;
    float p = c * (1.0f / 65536.0f);
    float h = p * logf(p + 1e-20f);

    float a = ncs, b = h;
#pragma unroll
    for (int off = 32; off > 0; off >>= 1) {
        a += __shfl_xor(a, off, 64);
        b += __shfl_xor(b, off, 64);
    }
    __shared__ float sa[4], sb[4];
    if (lane == 0) { sa[wave] = a; sb[wave] = b; }
    __syncthreads();
    if (threadIdx.x == 0) {
        float ta = (sa[0] + sa[1]) + (sa[2] + sa[3]);
        float tb = (sb[0] + sb[1]) + (sb[2] + sb[3]);
        atomicAdd(&scal[2], ta);   // n
        atomicAdd(&scal[1], tb);   // sum p*log(p+eps)
    }
}

// ---------------- finalize: new_un, new_e, loss, perplexity ----------------
__global__ __launch_bounds__(256) void k_final(const float* __restrict__ sums,
                                               const float* __restrict__ un,
                                               const float* __restrict__ ncs,
                                               const float* __restrict__ scal,
                                               float* __restrict__ out_ne,
                                               float* __restrict__ out_nun,
                                               float* __restrict__ out_loss,
                                               float* __restrict__ out_ppl) {
    const int i = blockIdx.x * 256 + threadIdx.x;  // i = d*K + k
    const int d = i >> 12;
    const int k = i & (K - 1);
    float nun = 0.1f * sums[k * D + d] + 0.9f * un[i];
    out_nun[i] = nun;
    float n = scal[2];
    float stable = (ncs[k] + 1e-20f) / (n + (float)K * 1e-20f) * n;
    out_ne[i] = nun / stable;
    if (i == 0) {
        out_loss[0] = 0.25f * (scal[0] * (1.0f / 4194304.0f));
        out_ppl[0] = expf(-scal[1]);
    }
}

extern "C" void kernel_launch(void* const* d_in, const int* in_sizes, int n_in,
                              void* d_out, int out_size, void* d_ws, size_t ws_size,
                              hipStream_t stream) {
    const float* x  = (const float*)d_in[0];
    const float* e  = (const float*)d_in[1];
    const float* cs = (const float*)d_in[2];
    const float* un = (const float*)d_in[3];

    float* ws = (float*)d_ws;
    float* counts = ws + WS_COUNTS;
    float* sums   = ws + WS_SUMS;
    float* scal   = ws + WS_SCAL;
    float* e2     = ws + WS_E2;
    float* et     = ws + WS_ET;
    int*   enc    = (int*)(ws + WS_ENC);

    float* out      = (float*)d_out;
    float* out_q    = out;                          // [N,D]
    float* out_loss = out + (size_t)N * D;          // scalar
    float* out_ppl  = out_loss + 1;                 // scalar
    float* out_ne   = out_ppl + 1;                  // [D,K]
    float* out_ncs  = out_ne + (size_t)D * K;       // [K]
    float* out_nun  = out_ncs + K;                  // [D,K]

    hipMemsetAsync(d_ws, 0, (size_t)WS_ZERO_FLOATS * sizeof(float), stream);
    k_transpose<<<D * K / 256, 256, 0, stream>>>(e, et);
    k_e2<<<K / 256, 256, 0, stream>>>(e, e2);
    k_argmin<<<N / 64, 256, 0, stream>>>(x, et, e2, enc);
    k_scatter<<<N / 4, 256, 0, stream>>>(x, et, enc, out_q, counts, sums, scal);
    k_stats<<<K / 256, 256, 0, stream>>>(counts, cs, out_ncs, scal);
    k_final<<<D * K / 256, 256, 0, stream>>>(sums, un, out_ncs, scal,
                                             out_ne, out_nun, out_loss, out_ppl);
}

// Round 2
// 617.339 us; speedup vs baseline: 2.5088x; 2.5088x over previous
//
#include <hip/hip_runtime.h>
#include <math.h>

#define D 64
#define K 4096
#define N 65536

typedef float f32x2 __attribute__((ext_vector_type(2)));

#if __has_builtin(__builtin_elementwise_fma)
#define FMA2(a, b, c) __builtin_elementwise_fma(a, b, c)
#else
static __device__ inline f32x2 FMA2(f32x2 a, f32x2 b, f32x2 c) {
    c.x = fmaf(a.x, b.x, c.x);
    c.y = fmaf(a.y, b.y, c.y);
    return c;
}
#endif

// ---------------- ws layout (in floats) ----------------
#define WS_COUNTS 0
#define WS_SUMS   (WS_COUNTS + K)
#define WS_SCAL   (WS_SUMS + K * D)          // 0=loss, 1=entropy_acc, 2=n_acc
#define WS_E2     (WS_SCAL + 8)
#define WS_ET     (WS_E2 + K)
#define WS_ENC    (WS_ET + K * D)
#define WS_LOSSP  (WS_ENC + N)               // 1024 per-block loss partials
#define WS_ZERO_FLOATS (WS_SCAL + 8)         // zero counts+sums+scalars

#define SCATTER_BLOCKS 1024
#define SCATTER_WAVES  (SCATTER_BLOCKS * 4)

// ---------------- prep: transpose e [D,K] -> e_t [K,D] ----------------
__global__ __launch_bounds__(256) void k_transpose(const float* __restrict__ e,
                                                   float* __restrict__ et) {
    int i = blockIdx.x * 256 + threadIdx.x;   // i = d*K + k (k fastest)
    int d = i >> 12;
    int k = i & (K - 1);
    et[k * D + d] = e[i];
}

// ---------------- prep: e2[k] = sum_d e[d][k]^2 ----------------
__global__ __launch_bounds__(256) void k_e2(const float* __restrict__ e,
                                            float* __restrict__ e2) {
    int k = blockIdx.x * 256 + threadIdx.x;
    float a = 0.0f;
    for (int d = 0; d < D; ++d) {
        float v = e[d * K + k];
        a = fmaf(v, v, a);
    }
    e2[k] = a;
}

// ---------------- main: per-token argmin over K codes ----------------
// lane = token (64 tokens/block), each wave covers a K-quarter.
// et row address is wave-uniform -> scalar loads; FMAs in packed f32x2.
__global__ __launch_bounds__(256) void k_argmin(const float* __restrict__ x,
                                                const float* __restrict__ et,
                                                const float* __restrict__ e2,
                                                int* __restrict__ enc) {
    const int lane = threadIdx.x & 63;
    const int wave = __builtin_amdgcn_readfirstlane(threadIdx.x >> 6);
    const int tokBase = blockIdx.x * 64;
    const int tok = tokBase + lane;

    // x row resident in 32 packed VGPR pairs
    f32x2 xr[32];
    const f32x2* xp = (const f32x2*)(x + (size_t)tok * D);
#pragma unroll
    for (int j = 0; j < 32; ++j) xr[j] = xp[j];

    float best = 3.4e38f;
    int bidx = 0;
    const int k0 = wave * (K / 4);
#pragma unroll 2
    for (int k = k0; k < k0 + K / 4; ++k) {
        const f32x2* q = (const f32x2*)(et + (size_t)k * D);  // uniform -> s_load
        f32x2 a0 = {0.f, 0.f}, a1 = {0.f, 0.f}, a2 = {0.f, 0.f}, a3 = {0.f, 0.f};
#pragma unroll
        for (int j = 0; j < 8; ++j) {
            a0 = FMA2(xr[4 * j + 0], q[4 * j + 0], a0);
            a1 = FMA2(xr[4 * j + 1], q[4 * j + 1], a1);
            a2 = FMA2(xr[4 * j + 2], q[4 * j + 2], a2);
            a3 = FMA2(xr[4 * j + 3], q[4 * j + 3], a3);
        }
        f32x2 s = (a0 + a1) + (a2 + a3);
        float dot = s.x + s.y;
        float dist = fmaf(-2.0f, dot, e2[k]);  // x^2 omitted: constant per row
        if (dist < best) { best = dist; bidx = k; }   // strict < -> first index
    }

    // combine the 4 K-quarters (ascending wave = ascending k: ties keep first)
    __shared__ float sval[4][64];
    __shared__ int   sidx[4][64];
    sval[wave][lane] = best;
    sidx[wave][lane] = bidx;
    __syncthreads();
    if (threadIdx.x < 64) {
        float bv = sval[0][lane];
        int   bi = sidx[0][lane];
#pragma unroll
        for (int w = 1; w < 4; ++w) {
            float v = sval[w][lane];
            int   i2 = sidx[w][lane];
            if (v < bv) { bv = v; bi = i2; }
        }
        enc[tokBase + lane] = bi;
    }
}

// ---------------- gather/scatter: quantized_st, loss partials, counts, sums --
// grid-stride: wave w handles tokens w, w+4096, ... (16 each). lane = d.
// Loss goes to a per-block partial (NO same-address global atomics).
__global__ __launch_bounds__(256) void k_scatter(const float* __restrict__ x,
                                                 const float* __restrict__ et,
                                                 const int* __restrict__ enc,
                                                 float* __restrict__ out_q,
                                                 float* __restrict__ counts,
                                                 float* __restrict__ sums,
                                                 float* __restrict__ lossp) {
    const int lane = threadIdx.x & 63;
    const int wave = __builtin_amdgcn_readfirstlane(threadIdx.x >> 6);
    const int wid = blockIdx.x * 4 + wave;

    float lacc = 0.0f;
    for (int tok = wid; tok < N; tok += SCATTER_WAVES) {
        const int idx = enc[tok];                 // wave-uniform -> scalar load
        const float xv = x[(size_t)tok * D + lane];
        const float qv = et[(size_t)idx * D + lane];
        float t = qv - xv;                        // quantized - x
        out_q[(size_t)tok * D + lane] = xv + t;   // straight-through
        lacc = fmaf(t, t, lacc);
        atomicAdd(&sums[(size_t)idx * D + lane], xv);
        if (lane == 0) atomicAdd(&counts[idx], 1.0f);
    }

    // wave reduce
#pragma unroll
    for (int off = 32; off > 0; off >>= 1) lacc += __shfl_xor(lacc, off, 64);
    __shared__ float sl[4];
    if (lane == 0) sl[wave] = lacc;
    __syncthreads();
    if (threadIdx.x == 0)
        lossp[blockIdx.x] = (sl[0] + sl[1]) + (sl[2] + sl[3]);
}

// ---------------- per-k stats: new_cs, partial n, partial entropy ----------
// block 0 additionally reduces the loss partials into scal[0].
__global__ __launch_bounds__(256) void k_stats(const float* __restrict__ counts,
                                               const float* __restrict__ cs,
                                               const float* __restrict__ lossp,
                                               float* __restrict__ out_ncs,
                                               float* __restrict__ scal) {
    const int k = blockIdx.x * 256 + threadIdx.x;
    const int lane = threadIdx.x & 63;
    const int wave = threadIdx.x >> 6;
    float c = counts[k];
    float ncs = 0.1f * c + 0.9f * cs[k];
    out_ncs[k] = ncs;
    float p = c * (1.0f / 65536.0f);
    float h = p * logf(p + 1e-20f);

    float a = ncs, b = h;
#pragma unroll
    for (int off = 32; off > 0; off >>= 1) {
        a += __shfl_xor(a, off, 64);
        b += __shfl_xor(b, off, 64);
    }
    __shared__ float sa[4], sb[4];
    if (lane == 0) { sa[wave] = a; sb[wave] = b; }
    __syncthreads();
    if (threadIdx.x == 0) {
        float ta = (sa[0] + sa[1]) + (sa[2] + sa[3]);
        float tb = (sb[0] + sb[1]) + (sb[2] + sb[3]);
        atomicAdd(&scal[2], ta);   // n
        atomicAdd(&scal[1], tb);   // sum p*log(p+eps)
    }

    if (blockIdx.x == 0) {
        // reduce 1024 loss partials; only block 0 touches scal[0]
        float l = 0.0f;
#pragma unroll
        for (int j = 0; j < SCATTER_BLOCKS / 256; ++j)
            l += lossp[threadIdx.x + j * 256];
#pragma unroll
        for (int off = 32; off > 0; off >>= 1) l += __shfl_xor(l, off, 64);
        __shared__ float sc[4];
        if (lane == 0) sc[wave] = l;
        __syncthreads();
        if (threadIdx.x == 0)
            scal[0] = (sc[0] + sc[1]) + (sc[2] + sc[3]);
    }
}

// ---------------- finalize: new_un, new_e, loss, perplexity ----------------
__global__ __launch_bounds__(256) void k_final(const float* __restrict__ sums,
                                               const float* __restrict__ un,
                                               const float* __restrict__ ncs,
                                               const float* __restrict__ scal,
                                               float* __restrict__ out_ne,
                                               float* __restrict__ out_nun,
                                               float* __restrict__ out_loss,
                                               float* __restrict__ out_ppl) {
    const int i = blockIdx.x * 256 + threadIdx.x;  // i = d*K + k
    const int d = i >> 12;
    const int k = i & (K - 1);
    float nun = 0.1f * sums[k * D + d] + 0.9f * un[i];
    out_nun[i] = nun;
    float n = scal[2];
    float stable = (ncs[k] + 1e-20f) / (n + (float)K * 1e-20f) * n;
    out_ne[i] = nun / stable;
    if (i == 0) {
        out_loss[0] = 0.25f * (scal[0] * (1.0f / 4194304.0f));
        out_ppl[0] = expf(-scal[1]);
    }
}

extern "C" void kernel_launch(void* const* d_in, const int* in_sizes, int n_in,
                              void* d_out, int out_size, void* d_ws, size_t ws_size,
                              hipStream_t stream) {
    const float* x  = (const float*)d_in[0];
    const float* e  = (const float*)d_in[1];
    const float* cs = (const float*)d_in[2];
    const float* un = (const float*)d_in[3];

    float* ws = (float*)d_ws;
    float* counts = ws + WS_COUNTS;
    float* sums   = ws + WS_SUMS;
    float* scal   = ws + WS_SCAL;
    float* e2     = ws + WS_E2;
    float* et     = ws + WS_ET;
    int*   enc    = (int*)(ws + WS_ENC);
    float* lossp  = ws + WS_LOSSP;

    float* out      = (float*)d_out;
    float* out_q    = out;                          // [N,D]
    float* out_loss = out + (size_t)N * D;          // scalar
    float* out_ppl  = out_loss + 1;                 // scalar
    float* out_ne   = out_ppl + 1;                  // [D,K]
    float* out_ncs  = out_ne + (size_t)D * K;       // [K]
    float* out_nun  = out_ncs + K;                  // [D,K]

    hipMemsetAsync(d_ws, 0, (size_t)WS_ZERO_FLOATS * sizeof(float), stream);
    k_transpose<<<D * K / 256, 256, 0, stream>>>(e, et);
    k_e2<<<K / 256, 256, 0, stream>>>(e, e2);
    k_argmin<<<N / 64, 256, 0, stream>>>(x, et, e2, enc);
    k_scatter<<<SCATTER_BLOCKS, 256, 0, stream>>>(x, et, enc, out_q, counts, sums, lossp);
    k_stats<<<K / 256, 256, 0, stream>>>(counts, cs, lossp, out_ncs, scal);
    k_final<<<D * K / 256, 256, 0, stream>>>(sums, un, out_ncs, scal,
                                             out_ne, out_nun, out_loss, out_ppl);
}

// Round 3
// 266.428 us; speedup vs baseline: 5.8131x; 2.3171x over previous
//
#include <hip/hip_runtime.h>
#include <math.h>

#define D 64
#define K 4096
#define N 65536

typedef short s16x8 __attribute__((ext_vector_type(8)));
typedef short s16x4 __attribute__((ext_vector_type(4)));
typedef float f32x4 __attribute__((ext_vector_type(4)));

// round-to-nearest-even f32 -> bf16 (as raw short)
static __device__ inline short bf16_rne(float v) {
    unsigned u = __float_as_uint(v);
    unsigned r = (u + 0x7FFFu + ((u >> 16) & 1u)) >> 16;
    return (short)r;
}
static __device__ inline float bf16_f(short s) {
    return __uint_as_float(((unsigned)(unsigned short)s) << 16);
}

// ---------------- ws layout (in float units) ----------------
#define WS_COUNTS 0
#define WS_SUMS   (WS_COUNTS + K)
#define WS_SCAL   (WS_SUMS + K * D)          // 0=loss, 1=entropy, 2=n
#define WS_BIAS   (WS_SCAL + 8)              // -0.5*sum(e^2) per k
#define WS_ET     (WS_BIAS + K)              // e transposed [K][D] fp32
#define WS_ENC    (WS_ET + K * D)            // N ints
#define WS_LOSSP  (WS_ENC + N)               // 1024 loss partials
#define WS_XH     (WS_LOSSP + 1024)          // N*D bf16 = N*D/2 floats
#define WS_XL     (WS_XH + N * D / 2)
#define WS_EH     (WS_XL + N * D / 2)        // K*D bf16 fragment-ordered
#define WS_EL     (WS_EH + K * D / 2)
#define WS_ZERO_FLOATS (WS_SCAL + 8)

#define SCATTER_BLOCKS 1024
#define SCATTER_WAVES  (SCATTER_BLOCKS * 4)

// ---------------- prep: transpose e [D,K] -> et [K,D] (for scatter gather) --
__global__ __launch_bounds__(256) void k_transpose(const float* __restrict__ e,
                                                   float* __restrict__ et) {
    int i = blockIdx.x * 256 + threadIdx.x;   // i = d*K + k
    int d = i >> 12;
    int k = i & (K - 1);
    et[k * D + d] = e[i];
}

// ---------------- prep: bias[k] = -0.5 * sum_d e[d][k]^2 ----------------
__global__ __launch_bounds__(256) void k_bias(const float* __restrict__ e,
                                              float* __restrict__ bias) {
    int k = blockIdx.x * 256 + threadIdx.x;
    float a = 0.0f;
    for (int d = 0; d < D; ++d) {
        float v = e[d * K + k];
        a = fmaf(v, v, a);
    }
    bias[k] = -0.5f * a;
}

// ---------------- prep: split x into bf16 hi/lo, [N][D] row-major ----------
__global__ __launch_bounds__(256) void k_split_x(const float* __restrict__ x,
                                                 short* __restrict__ xh,
                                                 short* __restrict__ xl) {
    int i = blockIdx.x * 256 + threadIdx.x;   // one float4 per thread
    const float4 v = ((const float4*)x)[i];
    s16x4 h, l;
    h.x = bf16_rne(v.x); l.x = bf16_rne(v.x - bf16_f(h.x));
    h.y = bf16_rne(v.y); l.y = bf16_rne(v.y - bf16_f(h.y));
    h.z = bf16_rne(v.z); l.z = bf16_rne(v.z - bf16_f(h.z));
    h.w = bf16_rne(v.w); l.w = bf16_rne(v.w - bf16_f(h.w));
    ((s16x4*)xh)[i] = h;
    ((s16x4*)xl)[i] = l;
}

// ---------------- prep: e -> B-fragment-ordered bf16 hi/lo ----------------
// eh[((t*2+c)*64 + l)*8 + j] = bf16(e[(c*32 + (l>>4)*8 + j)][t*16 + (l&15)])
__global__ __launch_bounds__(256) void k_prep_e(const float* __restrict__ e,
                                                short* __restrict__ eh,
                                                short* __restrict__ el) {
    int gid = blockIdx.x * 256 + threadIdx.x;   // 32768 total: t*128 + c*64 + l
    int l = gid & 63;
    int c = (gid >> 6) & 1;
    int t = gid >> 7;
    int q = l >> 4;
    int n = l & 15;
    int d0 = c * 32 + q * 8;
    int k = t * 16 + n;
    s16x8 h, lo;
#pragma unroll
    for (int j = 0; j < 8; ++j) {
        float v = e[(size_t)(d0 + j) * K + k];
        short hh = bf16_rne(v);
        h[j] = hh;
        lo[j] = bf16_rne(v - bf16_f(hh));
    }
    ((s16x8*)eh)[gid] = h;
    ((s16x8*)el)[gid] = lo;
}

// ---------------- main: MFMA argmin ----------------
// wave = one 16-token tile; block = 4 waves = 64 tokens; K loop over 256
// 16-code tiles, e-tiles staged via LDS (shared by the block's 4 waves).
// score = dot(x,e) - e2/2 (acc init = bias), argmax == argmin of dist.
__global__ __launch_bounds__(256) void k_argmin_mfma(const short* __restrict__ xh,
                                                     const short* __restrict__ xl,
                                                     const short* __restrict__ eh,
                                                     const short* __restrict__ el,
                                                     const float* __restrict__ bias,
                                                     int* __restrict__ enc) {
    const int tid = threadIdx.x;
    const int lane = tid & 63;
    const int wave = tid >> 6;
    const int quad = lane >> 4;
    const int n = lane & 15;
    const int tok0 = (blockIdx.x * 4 + wave) * 16;

    // A fragments: a[c][s]  (c = D-chunk, s = 0 hi / 1 lo), resident all loop
    s16x8 aF[2][2];
#pragma unroll
    for (int c = 0; c < 2; ++c) {
        const size_t off = (size_t)(tok0 + n) * D + c * 32 + quad * 8;
        aF[c][0] = *(const s16x8*)(xh + off);
        aF[c][1] = *(const s16x8*)(xl + off);
    }

    __shared__ short sEH[1024];   // one e-tile: 2 chunks x 64 lanes x 8
    __shared__ short sEL[1024];

    const s16x8* ehv = (const s16x8*)eh;
    const s16x8* elv = (const s16x8*)el;

    // register prefetch of tile 0
    s16x8 stage = (tid < 128) ? ehv[tid] : elv[tid - 128];

    float bestv[4] = {-3.4e38f, -3.4e38f, -3.4e38f, -3.4e38f};
    int besti[4] = {0, 0, 0, 0};

    for (int t = 0; t < K / 16; ++t) {
        __syncthreads();                       // LDS free from previous tile
        if (tid < 128) *(s16x8*)&sEH[tid * 8] = stage;
        else           *(s16x8*)&sEL[(tid - 128) * 8] = stage;
        __syncthreads();
        if (t + 1 < K / 16)                    // prefetch next tile
            stage = (tid < 128) ? ehv[(t + 1) * 128 + tid]
                                : elv[(t + 1) * 128 + (tid - 128)];

        const s16x8 bh0 = *(const s16x8*)&sEH[lane * 8];
        const s16x8 bh1 = *(const s16x8*)&sEH[(64 + lane) * 8];
        const s16x8 bl0 = *(const s16x8*)&sEL[lane * 8];
        const s16x8 bl1 = *(const s16x8*)&sEL[(64 + lane) * 8];

        const float bb = bias[t * 16 + n];
        f32x4 acc = {bb, bb, bb, bb};
        acc = __builtin_amdgcn_mfma_f32_16x16x32_bf16(aF[0][0], bh0, acc, 0, 0, 0);
        acc = __builtin_amdgcn_mfma_f32_16x16x32_bf16(aF[1][0], bh1, acc, 0, 0, 0);
        acc = __builtin_amdgcn_mfma_f32_16x16x32_bf16(aF[0][0], bl0, acc, 0, 0, 0);
        acc = __builtin_amdgcn_mfma_f32_16x16x32_bf16(aF[1][0], bl1, acc, 0, 0, 0);
        acc = __builtin_amdgcn_mfma_f32_16x16x32_bf16(aF[0][1], bh0, acc, 0, 0, 0);
        acc = __builtin_amdgcn_mfma_f32_16x16x32_bf16(aF[1][1], bh1, acc, 0, 0, 0);

        const int kidx = t * 16 + n;
#pragma unroll
        for (int r = 0; r < 4; ++r) {
            bool gt = acc[r] > bestv[r];       // strict > : first max kept
            bestv[r] = gt ? acc[r] : bestv[r];
            besti[r] = gt ? kidx : besti[r];
        }
    }

    // reduce across the 16-lane column group (xor 1,2,4,8 stays in group)
#pragma unroll
    for (int off = 1; off < 16; off <<= 1) {
#pragma unroll
        for (int r = 0; r < 4; ++r) {
            float vv = __shfl_xor(bestv[r], off, 64);
            int ii = __shfl_xor(besti[r], off, 64);
            bool take = (vv > bestv[r]) || (vv == bestv[r] && ii < besti[r]);
            bestv[r] = take ? vv : bestv[r];
            besti[r] = take ? ii : besti[r];
        }
    }
    if (n == 0) {
#pragma unroll
        for (int r = 0; r < 4; ++r)
            enc[tok0 + quad * 4 + r] = besti[r];
    }
}

// ---------------- gather/scatter: quantized_st, loss partials, counts, sums --
__global__ __launch_bounds__(256) void k_scatter(const float* __restrict__ x,
                                                 const float* __restrict__ et,
                                                 const int* __restrict__ enc,
                                                 float* __restrict__ out_q,
                                                 float* __restrict__ counts,
                                                 float* __restrict__ sums,
                                                 float* __restrict__ lossp) {
    const int lane = threadIdx.x & 63;
    const int wave = __builtin_amdgcn_readfirstlane(threadIdx.x >> 6);
    const int wid = blockIdx.x * 4 + wave;

    float lacc = 0.0f;
    for (int tok = wid; tok < N; tok += SCATTER_WAVES) {
        const int idx = enc[tok];                 // wave-uniform -> scalar load
        const float xv = x[(size_t)tok * D + lane];
        const float qv = et[(size_t)idx * D + lane];
        float t = qv - xv;
        out_q[(size_t)tok * D + lane] = xv + t;   // straight-through
        lacc = fmaf(t, t, lacc);
        atomicAdd(&sums[(size_t)idx * D + lane], xv);
        if (lane == 0) atomicAdd(&counts[idx], 1.0f);
    }
#pragma unroll
    for (int off = 32; off > 0; off >>= 1) lacc += __shfl_xor(lacc, off, 64);
    __shared__ float sl[4];
    if (lane == 0) sl[wave] = lacc;
    __syncthreads();
    if (threadIdx.x == 0)
        lossp[blockIdx.x] = (sl[0] + sl[1]) + (sl[2] + sl[3]);
}

// ---------------- per-k stats + loss-partial reduce ----------------
__global__ __launch_bounds__(256) void k_stats(const float* __restrict__ counts,
                                               const float* __restrict__ cs,
                                               const float* __restrict__ lossp,
                                               float* __restrict__ out_ncs,
                                               float* __restrict__ scal) {
    const int k = blockIdx.x * 256 + threadIdx.x;
    const int lane = threadIdx.x & 63;
    const int wave = threadIdx.x >> 6;
    float c = counts[k];
    float ncs = 0.1f * c + 0.9f * cs[k];
    out_ncs[k] = ncs;
    float p = c * (1.0f / 65536.0f);
    float h = p * logf(p + 1e-20f);

    float a = ncs, b = h;
#pragma unroll
    for (int off = 32; off > 0; off >>= 1) {
        a += __shfl_xor(a, off, 64);
        b += __shfl_xor(b, off, 64);
    }
    __shared__ float sa[4], sb[4];
    if (lane == 0) { sa[wave] = a; sb[wave] = b; }
    __syncthreads();
    if (threadIdx.x == 0) {
        atomicAdd(&scal[2], (sa[0] + sa[1]) + (sa[2] + sa[3]));
        atomicAdd(&scal[1], (sb[0] + sb[1]) + (sb[2] + sb[3]));
    }

    if (blockIdx.x == 0) {
        float l = 0.0f;
#pragma unroll
        for (int j = 0; j < SCATTER_BLOCKS / 256; ++j)
            l += lossp[threadIdx.x + j * 256];
#pragma unroll
        for (int off = 32; off > 0; off >>= 1) l += __shfl_xor(l, off, 64);
        __shared__ float sc[4];
        if (lane == 0) sc[wave] = l;
        __syncthreads();
        if (threadIdx.x == 0)
            scal[0] = (sc[0] + sc[1]) + (sc[2] + sc[3]);
    }
}

// ---------------- finalize ----------------
__global__ __launch_bounds__(256) void k_final(const float* __restrict__ sums,
                                               const float* __restrict__ un,
                                               const float* __restrict__ ncs,
                                               const float* __restrict__ scal,
                                               float* __restrict__ out_ne,
                                               float* __restrict__ out_nun,
                                               float* __restrict__ out_loss,
                                               float* __restrict__ out_ppl) {
    const int i = blockIdx.x * 256 + threadIdx.x;  // i = d*K + k
    const int d = i >> 12;
    const int k = i & (K - 1);
    float nun = 0.1f * sums[k * D + d] + 0.9f * un[i];
    out_nun[i] = nun;
    float nn = scal[2];
    float stable = (ncs[k] + 1e-20f) / (nn + (float)K * 1e-20f) * nn;
    out_ne[i] = nun / stable;
    if (i == 0) {
        out_loss[0] = 0.25f * (scal[0] * (1.0f / 4194304.0f));
        out_ppl[0] = expf(-scal[1]);
    }
}

extern "C" void kernel_launch(void* const* d_in, const int* in_sizes, int n_in,
                              void* d_out, int out_size, void* d_ws, size_t ws_size,
                              hipStream_t stream) {
    const float* x  = (const float*)d_in[0];
    const float* e  = (const float*)d_in[1];
    const float* cs = (const float*)d_in[2];
    const float* un = (const float*)d_in[3];

    float* ws = (float*)d_ws;
    float* counts = ws + WS_COUNTS;
    float* sums   = ws + WS_SUMS;
    float* scal   = ws + WS_SCAL;
    float* bias   = ws + WS_BIAS;
    float* et     = ws + WS_ET;
    int*   enc    = (int*)(ws + WS_ENC);
    float* lossp  = ws + WS_LOSSP;
    short* xh     = (short*)(ws + WS_XH);
    short* xl     = (short*)(ws + WS_XL);
    short* eh     = (short*)(ws + WS_EH);
    short* el     = (short*)(ws + WS_EL);

    float* out      = (float*)d_out;
    float* out_q    = out;                          // [N,D]
    float* out_loss = out + (size_t)N * D;
    float* out_ppl  = out_loss + 1;
    float* out_ne   = out_ppl + 1;                  // [D,K]
    float* out_ncs  = out_ne + (size_t)D * K;       // [K]
    float* out_nun  = out_ncs + K;                  // [D,K]

    hipMemsetAsync(d_ws, 0, (size_t)WS_ZERO_FLOATS * sizeof(float), stream);
    k_transpose<<<D * K / 256, 256, 0, stream>>>(e, et);
    k_bias<<<K / 256, 256, 0, stream>>>(e, bias);
    k_split_x<<<N * D / 4 / 256, 256, 0, stream>>>(x, xh, xl);
    k_prep_e<<<K / 16 * 128 / 256, 256, 0, stream>>>(e, eh, el);
    k_argmin_mfma<<<N / 64, 256, 0, stream>>>(xh, xl, eh, el, bias, enc);
    k_scatter<<<SCATTER_BLOCKS, 256, 0, stream>>>(x, et, enc, out_q, counts, sums, lossp);
    k_stats<<<K / 256, 256, 0, stream>>>(counts, cs, lossp, out_ncs, scal);
    k_final<<<D * K / 256, 256, 0, stream>>>(sums, un, out_ncs, scal,
                                             out_ne, out_nun, out_loss, out_ppl);
}